// Round 5
// baseline (121.876 us; speedup 1.0000x reference)
//
#include <hip/hip_runtime.h>
#include <hip/hip_bf16.h>

typedef __attribute__((ext_vector_type(4)))  float f32x4;
typedef __attribute__((ext_vector_type(16))) float f32x16;
typedef __attribute__((ext_vector_type(8)))  short bf16x8;

constexpr int IN_DIM  = 128;
constexpr int OUT_DIM = 128;
constexpr int BLOCK   = 256;                  // 4 waves
constexpr int ROWS_PER_BLOCK = 4 * 32;        // 128
constexpr size_t WS_V_BYTES = 16 * 128 * 8 * sizeof(ushort);  // 32 KB fragment-major v
constexpr size_t WS_NEED    = WS_V_BYTES + 128 * sizeof(float);

// v[o][k] = sign(round(sign)) * 2^round(clamp(shift,-14,0))  (exact in bf16)
// One 8-wide bf16 fragment: row o=row, k = j*8 .. j*8+8
__device__ inline bf16x8 build_seg(const float* __restrict__ shiftp,
                                   const float* __restrict__ signp,
                                   int row, int j)
{
    const int g = row * IN_DIM + j * 8;
    f32x4 sh0 = *reinterpret_cast<const f32x4*>(shiftp + g);
    f32x4 sh1 = *reinterpret_cast<const f32x4*>(shiftp + g + 4);
    f32x4 sg0 = *reinterpret_cast<const f32x4*>(signp + g);
    f32x4 sg1 = *reinterpret_cast<const f32x4*>(signp + g + 4);
    union { ushort u[8]; bf16x8 v; } tmp;
    #pragma unroll
    for (int e = 0; e < 8; ++e) {
        float sh = (e < 4) ? sh0[e] : sh1[e - 4];
        float sg = (e < 4) ? sg0[e] : sg1[e - 4];
        sh = fminf(fmaxf(sh, -14.0f), 0.0f);
        const int   si = (int)rintf(sh);      // round-half-even like jnp.round
        const float rs = rintf(sg);           // {-1, 0, 1}
        ushort bits = 0;
        if (rs != 0.0f)
            bits = (ushort)(((rs < 0.0f) ? 0x8000u : 0u) |
                            (unsigned)((127 + si) << 7));  // exact 2^si in bf16
        tmp.u[e] = bits;
    }
    return tmp.v;
}

// Pre-kernel: build v (fragment-major: [kidx 0..15][row 0..127] 16B frags) + bq into ws.
__global__ void build_kernel(const float* __restrict__ shiftp,
                             const float* __restrict__ signp,
                             const float* __restrict__ biasp,
                             ushort* __restrict__ wsv, float* __restrict__ wsb)
{
    const int seg = blockIdx.x * 256 + threadIdx.x;   // 8 blocks -> 2048 segs
    const int row = seg >> 4;
    const int j   = seg & 15;
    bf16x8 v = build_seg(shiftp, signp, row, j);
    *reinterpret_cast<bf16x8*>(&wsv[(j * OUT_DIM + row) * 8]) = v;
    if (blockIdx.x == 0 && threadIdx.x < OUT_DIM)
        wsb[threadIdx.x] = floorf(biasp[threadIdx.x] * 65536.0f) * (1.0f / 65536.0f);
}

// Main: mfma_f32_32x32x16_bf16, A = x rows (m), B = v^T (k x o).
// D: col = lane&31 = o_local, row m = (reg&3) + 8*(reg>>2) + 4*(lane>>5).
// => one store_dword: lanes 0-31 write one FULL 128B line (32 floats of one row).
template<bool PRE>
__global__ __launch_bounds__(BLOCK, 4)
void linshift_main(const float* __restrict__ x,
                   const float* __restrict__ shiftp,
                   const float* __restrict__ signp,
                   const float* __restrict__ biasp,
                   const ushort* __restrict__ wsv,
                   const float* __restrict__ wsb,
                   float* __restrict__ out)
{
    __shared__ ushort v_lds[16 * OUT_DIM * 8];   // 32 KB, fragment-major
    __shared__ float  b_lds[OUT_DIM];

    const int t = threadIdx.x;
    if (PRE) {
        const f32x4* src = reinterpret_cast<const f32x4*>(wsv);
        f32x4*       dst = reinterpret_cast<f32x4*>(v_lds);
        #pragma unroll
        for (int i = 0; i < 8; ++i) dst[t + i * 256] = src[t + i * 256];
        if (t < OUT_DIM) b_lds[t] = wsb[t];
    } else {
        #pragma unroll
        for (int s = 0; s < 8; ++s) {
            const int seg = t + s * 256;
            const int row = seg >> 4, j = seg & 15;
            bf16x8 v = build_seg(shiftp, signp, row, j);
            *reinterpret_cast<bf16x8*>(&v_lds[(j * OUT_DIM + row) * 8]) = v;
        }
        if (t < OUT_DIM) b_lds[t] = floorf(biasp[t] * 65536.0f) * (1.0f / 65536.0f);
    }
    __syncthreads();

    const int wave = t >> 6, lane = t & 63;
    const int ml = lane & 31;      // A row (x-row) for loads; D col (o_local) for stores
    const int hi = lane >> 5;

    const long long row0 = (long long)blockIdx.x * ROWS_PER_BLOCK + wave * 32;
    const float* xp = x + (row0 + ml) * IN_DIM + hi * 8;

    // A fragments: a[ks] = x[row0+ml][ks*16 + hi*8 .. +8] as bf16
    bf16x8 a[8];
    #pragma unroll
    for (int half = 0; half < 2; ++half) {
        f32x4 f[8];
        #pragma unroll
        for (int q = 0; q < 4; ++q) {
            const int ks = half * 4 + q;
            f[2 * q]     = *reinterpret_cast<const f32x4*>(xp + ks * 16);
            f[2 * q + 1] = *reinterpret_cast<const f32x4*>(xp + ks * 16 + 4);
        }
        #pragma unroll
        for (int q = 0; q < 4; ++q) {
            union { ushort u[8]; bf16x8 v; } tmp;
            #pragma unroll
            for (int e = 0; e < 4; ++e) {
                __hip_bfloat16 h0 = __float2bfloat16(f[2 * q][e]);
                __hip_bfloat16 h1 = __float2bfloat16(f[2 * q + 1][e]);
                tmp.u[e]     = *reinterpret_cast<const ushort*>(&h0);
                tmp.u[e + 4] = *reinterpret_cast<const ushort*>(&h1);
            }
            a[half * 4 + q] = tmp.v;
        }
    }

    float* op = out + row0 * OUT_DIM;
    #pragma unroll
    for (int ct = 0; ct < 4; ++ct) {
        const float bv = b_lds[ct * 32 + ml];   // bias folds into acc init (col-only dep)
        f32x16 acc;
        #pragma unroll
        for (int r = 0; r < 16; ++r) acc[r] = bv;

        #pragma unroll
        for (int ks = 0; ks < 8; ++ks) {
            // B fragment: v^T[k = ks*16+hi*8 ..][o = ct*32+ml] = v[o][k..k+8]
            bf16x8 vb = *reinterpret_cast<const bf16x8*>(
                &v_lds[((ks * 2 + hi) * OUT_DIM + ct * 32 + ml) * 8]);
            acc = __builtin_amdgcn_mfma_f32_32x32x16_bf16(a[ks], vb, acc, 0, 0, 0);
        }

        // store: per (ct, r) instruction = 2 full 128B lines (rows m, m+4... hi split)
        #pragma unroll
        for (int r = 0; r < 16; ++r) {
            const int m = (r & 3) + 8 * (r >> 2) + 4 * hi;
            op[(long long)m * OUT_DIM + ct * 32 + ml] = acc[r];
        }
    }
}

extern "C" void kernel_launch(void* const* d_in, const int* in_sizes, int n_in,
                              void* d_out, int out_size, void* d_ws, size_t ws_size,
                              hipStream_t stream) {
    const float* x  = (const float*)d_in[0];
    const float* sh = (const float*)d_in[1];
    const float* sg = (const float*)d_in[2];
    const float* b  = (const float*)d_in[3];
    float* out = (float*)d_out;

    const int N = in_sizes[0] / IN_DIM;          // 524288
    const int grid = N / ROWS_PER_BLOCK;         // 4096 (exact)

    if (ws_size >= WS_NEED) {
        ushort* wsv = (ushort*)d_ws;
        float*  wsb = (float*)((char*)d_ws + WS_V_BYTES);
        build_kernel<<<8, 256, 0, stream>>>(sh, sg, b, wsv, wsb);
        linshift_main<true><<<grid, BLOCK, 0, stream>>>(x, sh, sg, b, wsv, wsb, out);
    } else {
        linshift_main<false><<<grid, BLOCK, 0, stream>>>(x, sh, sg, b,
                                                         nullptr, nullptr, out);
    }
}

// Round 7
// 116.114 us; speedup vs baseline: 1.0496x; 1.0496x over previous
//
#include <hip/hip_runtime.h>
#include <hip/hip_bf16.h>
#include <stdint.h>

typedef __attribute__((ext_vector_type(4)))  float f32x4;
typedef __attribute__((ext_vector_type(16))) float f32x16;
typedef __attribute__((ext_vector_type(8)))  short bf16x8;

constexpr int IN_DIM  = 128;
constexpr int OUT_DIM = 128;
constexpr int BLOCK   = 256;              // 4 waves; wave w owns out cols w*32..+32
constexpr int TILE_ROWS = 32;             // 16 KB of f32 x per tile
constexpr int TILES_PER_BLOCK = 8;        // 256 rows per block
constexpr int ROWS_PER_BLOCK = TILE_ROWS * TILES_PER_BLOCK;
constexpr int NBUF = 3;                   // 48 KB LDS -> 3 blocks/CU
constexpr size_t WS_V_BYTES = OUT_DIM * IN_DIM * sizeof(ushort);  // 32 KB row-major bf16 v
constexpr size_t WS_NEED    = WS_V_BYTES;

#define WAITV4() asm volatile("s_waitcnt vmcnt(4)" ::: "memory")

// v[o][k] = sign(round(sign)) * 2^round(clamp(shift,-14,0))  (exact in bf16)
__device__ __forceinline__ bf16x8 build_seg(const float* __restrict__ shiftp,
                                            const float* __restrict__ signp,
                                            int row, int j)
{
    const int g = row * IN_DIM + j * 8;
    f32x4 sh0 = *reinterpret_cast<const f32x4*>(shiftp + g);
    f32x4 sh1 = *reinterpret_cast<const f32x4*>(shiftp + g + 4);
    f32x4 sg0 = *reinterpret_cast<const f32x4*>(signp + g);
    f32x4 sg1 = *reinterpret_cast<const f32x4*>(signp + g + 4);
    union { ushort u[8]; bf16x8 v; } tmp;
    #pragma unroll
    for (int e = 0; e < 8; ++e) {
        float sh = (e < 4) ? sh0[e] : sh1[e - 4];
        float sg = (e < 4) ? sg0[e] : sg1[e - 4];
        sh = fminf(fmaxf(sh, -14.0f), 0.0f);
        const int   si = (int)rintf(sh);      // round-half-even like jnp.round
        const float rs = rintf(sg);           // {-1, 0, 1}
        ushort bits = 0;
        if (rs != 0.0f)
            bits = (ushort)(((rs < 0.0f) ? 0x8000u : 0u) |
                            (unsigned)((127 + si) << 7));  // exact 2^si in bf16
        tmp.u[e] = bits;
    }
    return tmp.v;
}

// Pre-kernel: build row-major bf16 v[o][k] (32 KB) into ws.
__global__ void build_kernel(const float* __restrict__ shiftp,
                             const float* __restrict__ signp,
                             ushort* __restrict__ wsv)
{
    const int seg = blockIdx.x * 256 + threadIdx.x;   // 8 blocks -> 2048 segs of 8
    bf16x8 v = build_seg(shiftp, signp, seg >> 4, seg & 15);
    *reinterpret_cast<bf16x8*>(&wsv[seg * 8]) = v;
}

// Coalesced global -> LDS stage of one 32x128 f32 tile (16 KB), with XOR
// pre-swizzle on the GLOBAL side (rule #21): LDS chunk (row, c') holds global
// chunk (row, c' ^ (row&7)); the fragment read applies the same XOR.
// Each gll instruction: wave-uniform LDS base + lane*16B = 1024 B (256 floats).
__device__ __forceinline__ void stage_tile(const float* __restrict__ gtile,
                                           float* __restrict__ lbuf,
                                           int wave, int lane)
{
    #pragma unroll
    for (int i = 0; i < 4; ++i) {
        const int seg = wave * 4 + i;           // 16 segs of 1 KB per tile
        const int p   = seg * 64 + lane;        // 16B-chunk index 0..1023
        const int row = p >> 5;                 // 32 chunks per 512B row
        const int cl  = p & 31;
        const int cg  = cl ^ (row & 7);         // inverse swizzle on source
        const float* g = gtile + row * IN_DIM + cg * 4;
        __builtin_amdgcn_global_load_lds(
            (const __attribute__((address_space(1))) unsigned int*)(uintptr_t)g,
            (__attribute__((address_space(3))) unsigned int*)(uintptr_t)(lbuf + seg * 256),
            16, 0, 0);
    }
}

// Main: mfma_f32_32x32x16_bf16, A = x rows (from LDS), B = v^T (registers).
// D: col o = ct*32 + (lane&31), row m = (r&3) + 8*(r>>2) + 4*(lane>>5)
// -> each store_dword writes 2 full 128B lines. (Layout HW-verified round 5.)
template<bool PRE>
__global__ __launch_bounds__(BLOCK, 3)
void linshift_main(const float* __restrict__ x,
                   const float* __restrict__ shiftp,
                   const float* __restrict__ signp,
                   const float* __restrict__ biasp,
                   const ushort* __restrict__ wsv,
                   float* __restrict__ out)
{
    __shared__ float xbuf[NBUF][TILE_ROWS * IN_DIM];   // 3 x 16 KB

    const int t    = threadIdx.x;
    const int ct   = t >> 6;        // wave id = output column block
    const int lane = t & 63;
    const int ml   = lane & 31;     // A-row / D-col within 32
    const int hi   = lane >> 5;
    const int o    = ct * 32 + ml;  // this thread's output column

    // loop-invariant B fragments: vb[ks] = v[o][ks*16 + hi*8 .. +8]
    bf16x8 vb[8];
    if (PRE) {
        #pragma unroll
        for (int ks = 0; ks < 8; ++ks)
            vb[ks] = *reinterpret_cast<const bf16x8*>(&wsv[o * IN_DIM + ks * 16 + hi * 8]);
    } else {
        #pragma unroll
        for (int ks = 0; ks < 8; ++ks)
            vb[ks] = build_seg(shiftp, signp, o, ks * 2 + hi);
    }
    const float bv = floorf(biasp[o] * 65536.0f) * (1.0f / 65536.0f);  // round_to_fixed

    const long long brow0 = (long long)blockIdx.x * ROWS_PER_BLOCK;
    const float* xblock = x + brow0 * IN_DIM;

    // prologue: prefetch tiles 0 and 1
    stage_tile(xblock,                         xbuf[0], ct, lane);
    stage_tile(xblock + TILE_ROWS * IN_DIM,    xbuf[1], ct, lane);

    const int swz = ml & 7;
    #pragma unroll
    for (int tl = 0; tl < TILES_PER_BLOCK; ++tl) {
        // vmcnt(4): at most the 4 newest vmem ops outstanding -> gll(tl)
        // (older than everything recent) is definitely complete. Sound under
        // any store-retirement order.
        WAITV4();
        __builtin_amdgcn_s_barrier();            // all waves' gll(tl) done; tile readable;
        __builtin_amdgcn_sched_barrier(0);       // and everyone done reading tile tl-1

        if (tl + 2 < TILES_PER_BLOCK)
            stage_tile(xblock + (long long)(tl + 2) * TILE_ROWS * IN_DIM,
                       xbuf[(tl + 2) % NBUF], ct, lane);

        const float* buf = xbuf[tl % NBUF];

        // A fragments: row ml, k = ks*16 + hi*8 .. +8 (swizzled chunks)
        bf16x8 a[8];
        #pragma unroll
        for (int ks = 0; ks < 8; ++ks) {
            const int c0 = ks * 4 + hi * 2;                  // even chunk index
            f32x4 f0 = *reinterpret_cast<const f32x4*>(&buf[ml * IN_DIM + ((c0 ^ swz) << 2)]);
            f32x4 f1 = *reinterpret_cast<const f32x4*>(&buf[ml * IN_DIM + (((c0 + 1) ^ swz) << 2)]);
            union { ushort u[8]; bf16x8 v; } tmp;
            #pragma unroll
            for (int e = 0; e < 4; ++e) {
                __hip_bfloat16 h0 = __float2bfloat16(f0[e]);
                __hip_bfloat16 h1 = __float2bfloat16(f1[e]);
                tmp.u[e]     = *reinterpret_cast<const ushort*>(&h0);
                tmp.u[e + 4] = *reinterpret_cast<const ushort*>(&h1);
            }
            a[ks] = tmp.v;
        }

        f32x16 acc;
        #pragma unroll
        for (int r = 0; r < 16; ++r) acc[r] = bv;    // bias folded into acc init
        #pragma unroll
        for (int ks = 0; ks < 8; ++ks)
            acc = __builtin_amdgcn_mfma_f32_32x32x16_bf16(a[ks], vb[ks], acc, 0, 0, 0);

        float* op = out + (brow0 + (long long)tl * TILE_ROWS) * OUT_DIM + o;
        #pragma unroll
        for (int r = 0; r < 16; ++r) {
            const int m = (r & 3) + 8 * (r >> 2) + 4 * hi;
            op[m * OUT_DIM] = acc[r];
        }
        __builtin_amdgcn_sched_barrier(0);
    }
}

extern "C" void kernel_launch(void* const* d_in, const int* in_sizes, int n_in,
                              void* d_out, int out_size, void* d_ws, size_t ws_size,
                              hipStream_t stream) {
    const float* x  = (const float*)d_in[0];
    const float* sh = (const float*)d_in[1];
    const float* sg = (const float*)d_in[2];
    const float* b  = (const float*)d_in[3];
    float* out = (float*)d_out;

    const int N = in_sizes[0] / IN_DIM;            // 524288
    const int grid = N / ROWS_PER_BLOCK;           // 2048 (exact)

    if (ws_size >= WS_NEED) {
        ushort* wsv = (ushort*)d_ws;
        build_kernel<<<8, 256, 0, stream>>>(sh, sg, wsv);
        linshift_main<true><<<grid, BLOCK, 0, stream>>>(x, sh, sg, b, wsv, out);
    } else {
        linshift_main<false><<<grid, BLOCK, 0, stream>>>(x, sh, sg, b, nullptr, out);
    }
}